// Round 4
// baseline (691.911 us; speedup 1.0000x reference)
//
#include <hip/hip_runtime.h>

#define N_NODES  100000
#define N_EDGES  1200000
#define N_GRAPHS 1024
#define F        64
#define BN_EPS   1e-5f
#define NBUCK    ((N_NODES + 255) / 256)   // 391 buckets of 256 node IDs

// ---------------------------------------------------------------------------
// Step 1: bucket histogram (LDS-staged; 391 counters)
// ---------------------------------------------------------------------------
__global__ __launch_bounds__(256) void bhist(const int* __restrict__ dst,
                                             int* __restrict__ bcnt) {
  __shared__ int h[NBUCK];
  int t = threadIdx.x;
  for (int i = t; i < NBUCK; i += 256) h[i] = 0;
  __syncthreads();
  int i = blockIdx.x * blockDim.x + t;
  int n = gridDim.x * blockDim.x;
  for (int e = i; e < N_EDGES; e += n) atomicAdd(&h[dst[e] >> 8], 1);
  __syncthreads();
  for (int i2 = t; i2 < NBUCK; i2 += 256)
    if (h[i2]) atomicAdd(&bcnt[i2], h[i2]);
}

// ---------------------------------------------------------------------------
// Step 2: scan 391 bucket counts (one block)
// ---------------------------------------------------------------------------
__global__ __launch_bounds__(512) void bscan(const int* __restrict__ bcnt,
                                             int* __restrict__ bstart,
                                             int* __restrict__ bcur) {
  __shared__ int s[512];
  int t = threadIdx.x;
  int v = (t < NBUCK) ? bcnt[t] : 0;
  s[t] = v;
  __syncthreads();
  for (int off = 1; off < 512; off <<= 1) {
    int u = (t >= off) ? s[t - off] : 0;
    __syncthreads();
    s[t] += u;
    __syncthreads();
  }
  if (t < NBUCK) { int e = s[t] - v; bstart[t] = e; bcur[t] = e; }
  if (t == 0) bstart[NBUCK] = N_EDGES;
}

// ---------------------------------------------------------------------------
// Step 3: scatter packed (local_dst<<24 | src) into bucket regions.
// 391 open regions (~12KB each) -> L2 fills lines fully before eviction.
// ---------------------------------------------------------------------------
__global__ __launch_bounds__(256) void bscat(const int* __restrict__ src,
                                             const int* __restrict__ dst,
                                             int* __restrict__ bcur,
                                             int* __restrict__ pairs) {
  int i = blockIdx.x * blockDim.x + threadIdx.x;
  int n = gridDim.x * blockDim.x;
  for (int e = i; e < N_EDGES; e += n) {
    int d = dst[e];
    int pos = atomicAdd(&bcur[d >> 8], 1);
    pairs[pos] = (int)((((unsigned)d & 255u) << 24) | (unsigned)src[e]);
  }
}

// ---------------------------------------------------------------------------
// Step 4: per-bucket place. One block per bucket: LDS hist of local dst,
// LDS scan (produces rs!), LDS-cursor scatter into the block-owned,
// contiguous eidx region. Deletes the global 100k hist/scan pipeline.
// ---------------------------------------------------------------------------
__global__ __launch_bounds__(256) void place(const int* __restrict__ pairs,
                                             const int* __restrict__ bstart,
                                             int* __restrict__ rs,
                                             int* __restrict__ eidx) {
  __shared__ int lh[256];
  __shared__ int cur[256];
  int b = blockIdx.x, t = threadIdx.x;
  int nb0 = b << 8;
  int r0 = bstart[b], r1 = bstart[b + 1];

  lh[t] = 0;
  __syncthreads();
  for (int e = r0 + t; e < r1; e += 256)
    atomicAdd(&lh[((unsigned)pairs[e]) >> 24], 1);
  __syncthreads();

  int v = lh[t];
  cur[t] = v;
  __syncthreads();
  for (int off = 1; off < 256; off <<= 1) {       // Hillis-Steele inclusive
    int u = (t >= off) ? cur[t - off] : 0;
    __syncthreads();
    cur[t] += u;
    __syncthreads();
  }
  int excl = cur[t] - v;
  int node = nb0 + t;
  if (node < N_NODES) rs[node] = r0 + excl;
  if (b == 0 && t == 0) rs[N_NODES] = N_EDGES;
  __syncthreads();
  cur[t] = r0 + excl;                             // absolute cursor
  __syncthreads();

  for (int e = r0 + t; e < r1; e += 256) {
    unsigned p = (unsigned)pairs[e];
    int pos = atomicAdd(&cur[p >> 24], 1);
    eidx[pos] = (int)(p & 0xFFFFFFu);
  }
}

// ---------------------------------------------------------------------------
// Neighbor-mean gather. lane = 16*sub + f4: each float4 load covers 4
// neighbor rows (1KB/wave). Low VGPR -> high occupancy.
// ---------------------------------------------------------------------------
__global__ __launch_bounds__(256) void gather_mean(
    const float* __restrict__ feats, const int* __restrict__ rs,
    const int* __restrict__ eidx, float* __restrict__ mean) {
  int lane = threadIdx.x & 63;
  int wid  = (blockIdx.x * blockDim.x + threadIdx.x) >> 6;
  const int NW = (2048 * 256) >> 6;                 // 8192 waves
  const int per = (N_NODES + NW - 1) / NW;          // 13 nodes/wave
  int n0 = wid * per;
  int n1 = n0 + per; if (n1 > N_NODES) n1 = N_NODES;
  int fl  = lane & 15;
  int sub = lane >> 4;

  for (int n = n0; n < n1; n++) {
    int r0 = rs[n], r1 = rs[n + 1];
    float sx = 0.f, sy = 0.f, sz = 0.f, sw = 0.f;
    for (int base = r0; base < r1; base += 64) {
      int m = r1 - base; if (m > 64) m = 64;
      int myid = (lane < m) ? eidx[base + lane] : 0;
      for (int j = 0; j < m; j += 4) {
        int sid = __shfl(myid, j + sub);
        const float4 v =
            *(const float4*)(feats + (size_t)sid * F + 4 * fl);
        if (j + sub < m) { sx += v.x; sy += v.y; sz += v.z; sw += v.w; }
      }
    }
    sx += __shfl_xor(sx, 16); sy += __shfl_xor(sy, 16);
    sz += __shfl_xor(sz, 16); sw += __shfl_xor(sw, 16);
    sx += __shfl_xor(sx, 32); sy += __shfl_xor(sy, 32);
    sz += __shfl_xor(sz, 32); sw += __shfl_xor(sw, 32);
    float inv = 1.0f / fmaxf((float)(r1 - r0), 1.0f);
    if (sub == 0) {
      float4 mv = {sx * inv, sy * inv, sz * inv, sw * inv};
      *(float4*)(mean + (size_t)n * F + 4 * fl) = mv;
    }
  }
}

// ---------------------------------------------------------------------------
// SAGE update + ReLU + per-graph max. Weights pinned in 128 VGPRs.
// ---------------------------------------------------------------------------
__global__ __launch_bounds__(256, 2) void node_out(
    const float* __restrict__ feats, const float* __restrict__ mean,
    const float* __restrict__ Wself, const float* __restrict__ Wneigh,
    const float* __restrict__ bneigh, const int* __restrict__ gids,
    int* __restrict__ hgbits) {
  int lane = threadIdx.x & 63;
  int wid  = (blockIdx.x * blockDim.x + threadIdx.x) >> 6;
  const int NW = (512 * 256) >> 6;                  // 2048 waves
  const int per = (N_NODES + NW - 1) / NW;          // 49 nodes/wave
  int n0 = wid * per;
  int n1 = n0 + per; if (n1 > N_NODES) n1 = N_NODES;
  if (n0 >= n1) return;

  float wsv[F], wnv[F];
#pragma unroll
  for (int i = 0; i < F; i++) {
    wsv[i] = Wself[i * F + lane];
    wnv[i] = Wneigh[i * F + lane];
  }
  float bias = bneigh[lane];

  int curg = gids[n0];
  float gmax = 0.0f;
  for (int n = n0; n < n1; n++) {
    int g = gids[n];
    if (g != curg) {
      atomicMax(&hgbits[(size_t)curg * F + lane], __float_as_int(gmax));
      curg = g; gmax = 0.0f;
    }
    float f = feats[(size_t)n * F + lane];
    float m = mean[(size_t)n * F + lane];
    int fb = __float_as_int(f), mb = __float_as_int(m);
    float acc = bias;
#pragma unroll
    for (int i = 0; i < F; i++) {
      acc += __int_as_float(__builtin_amdgcn_readlane(fb, i)) * wsv[i];
      acc += __int_as_float(__builtin_amdgcn_readlane(mb, i)) * wnv[i];
    }
    gmax = fmaxf(gmax, fmaxf(acc, 0.0f));
  }
  atomicMax(&hgbits[(size_t)curg * F + lane], __float_as_int(gmax));
}

// ---------------------------------------------------------------------------
// MLP head: weights staged in LDS once, 8 graphs per block.
// ---------------------------------------------------------------------------
#define GPB 8
__global__ __launch_bounds__(128) void mlp(
    const float* __restrict__ hg,
    const float* __restrict__ W1, const float* __restrict__ b1,
    const float* __restrict__ g1, const float* __restrict__ be1,
    const float* __restrict__ rm1, const float* __restrict__ rv1,
    const float* __restrict__ W2, const float* __restrict__ b2,
    const float* __restrict__ g2, const float* __restrict__ be2,
    const float* __restrict__ rm2, const float* __restrict__ rv2,
    const float* __restrict__ W3, const float* __restrict__ b3,
    float* __restrict__ out) {
  __shared__ float W1s[64 * 128];
  __shared__ float W2s[128 * 64];
  __shared__ float W3s[64];
  __shared__ float sc1[128], sh1[128], b1s[128];
  __shared__ float sc2[64],  sh2[64],  b2s[64];
  __shared__ float s0[64], s1[128], s2[64];
  int t = threadIdx.x;

  for (int i = t; i < 64 * 128; i += 128) W1s[i] = W1[i];
  for (int i = t; i < 128 * 64; i += 128) W2s[i] = W2[i];
  if (t < 64) W3s[t] = W3[t];
  {
    float iv = rsqrtf(rv1[t] + BN_EPS);
    float sc = g1[t] * iv;
    sc1[t] = sc; sh1[t] = be1[t] - rm1[t] * sc; b1s[t] = b1[t];
  }
  if (t < 64) {
    float iv = rsqrtf(rv2[t] + BN_EPS);
    float sc = g2[t] * iv;
    sc2[t] = sc; sh2[t] = be2[t] - rm2[t] * sc; b2s[t] = b2[t];
  }
  __syncthreads();

  for (int gg = 0; gg < GPB; gg++) {
    int g = blockIdx.x * GPB + gg;
    if (t < 64) s0[t] = hg[(size_t)g * F + t];
    __syncthreads();
    {
      float acc = b1s[t];
      for (int i = 0; i < 64; i++) acc += s0[i] * W1s[i * 128 + t];
      acc = fmaxf(acc, 0.0f);
      s1[t] = acc * sc1[t] + sh1[t];
    }
    __syncthreads();
    if (t < 64) {
      float acc = b2s[t];
      for (int i = 0; i < 128; i++) acc += s1[i] * W2s[i * 64 + t];
      acc = fmaxf(acc, 0.0f);
      s2[t] = acc * sc2[t] + sh2[t];
    }
    __syncthreads();
    if (t < 64) {
      float p = s2[t] * W3s[t];
      for (int off = 32; off > 0; off >>= 1) p += __shfl_down(p, off);
      if (t == 0) out[g] = p + b3[0];
    }
    __syncthreads();
  }
}

// ---------------------------------------------------------------------------
extern "C" void kernel_launch(void* const* d_in, const int* in_sizes, int n_in,
                              void* d_out, int out_size, void* d_ws, size_t ws_size,
                              hipStream_t stream) {
  const float* feats  = (const float*)d_in[0];
  const int*   src    = (const int*)d_in[1];
  const int*   dst    = (const int*)d_in[2];
  const int*   gids   = (const int*)d_in[3];
  const float* Wself  = (const float*)d_in[4];
  const float* Wneigh = (const float*)d_in[5];
  const float* bneigh = (const float*)d_in[6];
  const float* W1  = (const float*)d_in[7];
  const float* b1  = (const float*)d_in[8];
  const float* g1  = (const float*)d_in[9];
  const float* be1 = (const float*)d_in[10];
  const float* rm1 = (const float*)d_in[11];
  const float* rv1 = (const float*)d_in[12];
  const float* W2  = (const float*)d_in[13];
  const float* b2  = (const float*)d_in[14];
  const float* g2  = (const float*)d_in[15];
  const float* be2 = (const float*)d_in[16];
  const float* rm2 = (const float*)d_in[17];
  const float* rv2 = (const float*)d_in[18];
  const float* W3  = (const float*)d_in[19];
  const float* b3  = (const float*)d_in[20];

  // ws layout: mean | rs | bstart | bcur | [bcnt | hgbits]=zeroed | pairs | eidx
  float* mean  = (float*)d_ws;                       // N_NODES*F (16B aligned)
  int* rs      = (int*)(mean + (size_t)N_NODES * F); // N_NODES+1
  int* bstart  = rs + (N_NODES + 1);                 // NBUCK+1
  int* bcur    = bstart + (NBUCK + 1);               // NBUCK
  int* bcnt    = bcur + NBUCK;                       // NBUCK      } zeroed
  int* hgbits  = bcnt + NBUCK;                       // N_GRAPHS*F } zeroed
  int* pairs   = hgbits + (size_t)N_GRAPHS * F;      // N_EDGES
  int* eidx    = pairs + N_EDGES;                    // N_EDGES

  hipMemsetAsync(bcnt, 0, (NBUCK + (size_t)N_GRAPHS * F) * sizeof(int), stream);

  bhist<<<512, 256, 0, stream>>>(dst, bcnt);
  bscan<<<1, 512, 0, stream>>>(bcnt, bstart, bcur);
  bscat<<<1024, 256, 0, stream>>>(src, dst, bcur, pairs);
  place<<<NBUCK, 256, 0, stream>>>(pairs, bstart, rs, eidx);
  gather_mean<<<2048, 256, 0, stream>>>(feats, rs, eidx, mean);
  node_out<<<512, 256, 0, stream>>>(feats, mean, Wself, Wneigh, bneigh,
                                    gids, hgbits);
  mlp<<<N_GRAPHS / GPB, 128, 0, stream>>>((const float*)hgbits,
                                          W1, b1, g1, be1, rm1, rv1,
                                          W2, b2, g2, be2, rm2, rv2, W3, b3,
                                          (float*)d_out);
}

// Round 5
// 283.157 us; speedup vs baseline: 2.4436x; 2.4436x over previous
//
#include <hip/hip_runtime.h>

#define N_NODES  100000
#define N_EDGES  1200000
#define N_GRAPHS 1024
#define F        64
#define BN_EPS   1e-5f
#define NBUCK    ((N_NODES + 255) / 256)     // 391 buckets of 256 node IDs
#define NBLK     512                          // scatter blocks (chunks)
#define CHUNK    ((N_EDGES + NBLK - 1) / NBLK) // 2344 edges per chunk

// ---------------------------------------------------------------------------
// Step 1: per-chunk bucket histogram. LDS counts, plain coalesced stores to
// Ct[block*NBUCK + bucket]. NO global atomics.
// ---------------------------------------------------------------------------
__global__ __launch_bounds__(256) void chist(const int* __restrict__ dst,
                                             int* __restrict__ Ct) {
  __shared__ int lh[NBUCK];
  int b = blockIdx.x, t = threadIdx.x;
  for (int i = t; i < NBUCK; i += 256) lh[i] = 0;
  __syncthreads();
  int e0 = b * CHUNK, e1 = e0 + CHUNK;
  if (e1 > N_EDGES) e1 = N_EDGES;
  for (int e = e0 + t; e < e1; e += 256) atomicAdd(&lh[dst[e] >> 8], 1);
  __syncthreads();
  for (int i = t; i < NBUCK; i += 256) Ct[(size_t)b * NBUCK + i] = lh[i];
}

// ---------------------------------------------------------------------------
// Step 2: per-bucket scan over the NBLK chunk counts -> intra-bucket
// exclusive prefix (in place) + bucket total. One block per bucket.
// ---------------------------------------------------------------------------
__global__ __launch_bounds__(NBLK) void cscan(int* __restrict__ Ct,
                                              int* __restrict__ bcnt) {
  __shared__ int s[NBLK];
  int i = blockIdx.x, t = threadIdx.x;
  int v = Ct[(size_t)t * NBUCK + i];
  s[t] = v;
  __syncthreads();
  for (int off = 1; off < NBLK; off <<= 1) {
    int u = (t >= off) ? s[t - off] : 0;
    __syncthreads();
    s[t] += u;
    __syncthreads();
  }
  Ct[(size_t)t * NBUCK + i] = s[t] - v;     // exclusive prefix within bucket
  if (t == NBLK - 1) bcnt[i] = s[NBLK - 1]; // bucket total
}

// ---------------------------------------------------------------------------
// Step 3: scan 391 bucket totals -> bstart. One block.
// ---------------------------------------------------------------------------
__global__ __launch_bounds__(512) void bscan(const int* __restrict__ bcnt,
                                             int* __restrict__ bstart) {
  __shared__ int s[512];
  int t = threadIdx.x;
  int v = (t < NBUCK) ? bcnt[t] : 0;
  s[t] = v;
  __syncthreads();
  for (int off = 1; off < 512; off <<= 1) {
    int u = (t >= off) ? s[t - off] : 0;
    __syncthreads();
    s[t] += u;
    __syncthreads();
  }
  if (t < NBUCK) bstart[t] = s[t] - v;
  if (t == 0) bstart[NBUCK] = N_EDGES;
}

// ---------------------------------------------------------------------------
// Step 4: deterministic scatter. Block b seeds LDS cursors from its reserved
// ranges (bstart + intra-bucket prefix), then places packed
// (local_dst<<24 | src) with LDS atomics only. Disjoint output sub-ranges.
// ---------------------------------------------------------------------------
__global__ __launch_bounds__(256) void cscat(const int* __restrict__ src,
                                             const int* __restrict__ dst,
                                             const int* __restrict__ Ct,
                                             const int* __restrict__ bstart,
                                             int* __restrict__ pairs) {
  __shared__ int cur[NBUCK];
  int b = blockIdx.x, t = threadIdx.x;
  for (int i = t; i < NBUCK; i += 256)
    cur[i] = bstart[i] + Ct[(size_t)b * NBUCK + i];
  __syncthreads();
  int e0 = b * CHUNK, e1 = e0 + CHUNK;
  if (e1 > N_EDGES) e1 = N_EDGES;
  for (int e = e0 + t; e < e1; e += 256) {
    int d = dst[e];
    int pos = atomicAdd(&cur[d >> 8], 1);
    pairs[pos] = (int)((((unsigned)d & 255u) << 24) | (unsigned)src[e]);
  }
}

// ---------------------------------------------------------------------------
// Step 5: per-bucket place. LDS hist of local dst, LDS scan (produces rs),
// LDS-cursor scatter into the block-owned contiguous eidx region.
// ---------------------------------------------------------------------------
__global__ __launch_bounds__(256) void place(const int* __restrict__ pairs,
                                             const int* __restrict__ bstart,
                                             int* __restrict__ rs,
                                             int* __restrict__ eidx) {
  __shared__ int lh[256];
  __shared__ int cur[256];
  int b = blockIdx.x, t = threadIdx.x;
  int nb0 = b << 8;
  int r0 = bstart[b], r1 = bstart[b + 1];

  lh[t] = 0;
  __syncthreads();
  for (int e = r0 + t; e < r1; e += 256)
    atomicAdd(&lh[((unsigned)pairs[e]) >> 24], 1);
  __syncthreads();

  int v = lh[t];
  cur[t] = v;
  __syncthreads();
  for (int off = 1; off < 256; off <<= 1) {
    int u = (t >= off) ? cur[t - off] : 0;
    __syncthreads();
    cur[t] += u;
    __syncthreads();
  }
  int excl = cur[t] - v;
  int node = nb0 + t;
  if (node < N_NODES) rs[node] = r0 + excl;
  if (b == 0 && t == 0) rs[N_NODES] = N_EDGES;
  __syncthreads();
  cur[t] = r0 + excl;
  __syncthreads();

  for (int e = r0 + t; e < r1; e += 256) {
    unsigned p = (unsigned)pairs[e];
    int pos = atomicAdd(&cur[p >> 24], 1);
    eidx[pos] = (int)(p & 0xFFFFFFu);
  }
}

// ---------------------------------------------------------------------------
// Neighbor-mean gather. lane = 16*sub + f4: each float4 load covers 4
// neighbor rows (1KB/wave). Low VGPR -> high occupancy.
// ---------------------------------------------------------------------------
__global__ __launch_bounds__(256) void gather_mean(
    const float* __restrict__ feats, const int* __restrict__ rs,
    const int* __restrict__ eidx, float* __restrict__ mean) {
  int lane = threadIdx.x & 63;
  int wid  = (blockIdx.x * blockDim.x + threadIdx.x) >> 6;
  const int NW = (2048 * 256) >> 6;                 // 8192 waves
  const int per = (N_NODES + NW - 1) / NW;          // 13 nodes/wave
  int n0 = wid * per;
  int n1 = n0 + per; if (n1 > N_NODES) n1 = N_NODES;
  int fl  = lane & 15;
  int sub = lane >> 4;

  for (int n = n0; n < n1; n++) {
    int r0 = rs[n], r1 = rs[n + 1];
    float sx = 0.f, sy = 0.f, sz = 0.f, sw = 0.f;
    for (int base = r0; base < r1; base += 64) {
      int m = r1 - base; if (m > 64) m = 64;
      int myid = (lane < m) ? eidx[base + lane] : 0;
      for (int j = 0; j < m; j += 4) {
        int sid = __shfl(myid, j + sub);
        const float4 v =
            *(const float4*)(feats + (size_t)sid * F + 4 * fl);
        if (j + sub < m) { sx += v.x; sy += v.y; sz += v.z; sw += v.w; }
      }
    }
    sx += __shfl_xor(sx, 16); sy += __shfl_xor(sy, 16);
    sz += __shfl_xor(sz, 16); sw += __shfl_xor(sw, 16);
    sx += __shfl_xor(sx, 32); sy += __shfl_xor(sy, 32);
    sz += __shfl_xor(sz, 32); sw += __shfl_xor(sw, 32);
    float inv = 1.0f / fmaxf((float)(r1 - r0), 1.0f);
    if (sub == 0) {
      float4 mv = {sx * inv, sy * inv, sz * inv, sw * inv};
      *(float4*)(mean + (size_t)n * F + 4 * fl) = mv;
    }
  }
}

// ---------------------------------------------------------------------------
// SAGE update + ReLU + per-graph max. Weights pinned in 128 VGPRs.
// ---------------------------------------------------------------------------
__global__ __launch_bounds__(256, 2) void node_out(
    const float* __restrict__ feats, const float* __restrict__ mean,
    const float* __restrict__ Wself, const float* __restrict__ Wneigh,
    const float* __restrict__ bneigh, const int* __restrict__ gids,
    int* __restrict__ hgbits) {
  int lane = threadIdx.x & 63;
  int wid  = (blockIdx.x * blockDim.x + threadIdx.x) >> 6;
  const int NW = (512 * 256) >> 6;                  // 2048 waves
  const int per = (N_NODES + NW - 1) / NW;          // 49 nodes/wave
  int n0 = wid * per;
  int n1 = n0 + per; if (n1 > N_NODES) n1 = N_NODES;
  if (n0 >= n1) return;

  float wsv[F], wnv[F];
#pragma unroll
  for (int i = 0; i < F; i++) {
    wsv[i] = Wself[i * F + lane];
    wnv[i] = Wneigh[i * F + lane];
  }
  float bias = bneigh[lane];

  int curg = gids[n0];
  float gmax = 0.0f;
  for (int n = n0; n < n1; n++) {
    int g = gids[n];
    if (g != curg) {
      atomicMax(&hgbits[(size_t)curg * F + lane], __float_as_int(gmax));
      curg = g; gmax = 0.0f;
    }
    float f = feats[(size_t)n * F + lane];
    float m = mean[(size_t)n * F + lane];
    int fb = __float_as_int(f), mb = __float_as_int(m);
    float acc = bias;
#pragma unroll
    for (int i = 0; i < F; i++) {
      acc += __int_as_float(__builtin_amdgcn_readlane(fb, i)) * wsv[i];
      acc += __int_as_float(__builtin_amdgcn_readlane(mb, i)) * wnv[i];
    }
    gmax = fmaxf(gmax, fmaxf(acc, 0.0f));
  }
  atomicMax(&hgbits[(size_t)curg * F + lane], __float_as_int(gmax));
}

// ---------------------------------------------------------------------------
// MLP head: weights staged in LDS once, 8 graphs per block.
// ---------------------------------------------------------------------------
#define GPB 8
__global__ __launch_bounds__(128) void mlp(
    const float* __restrict__ hg,
    const float* __restrict__ W1, const float* __restrict__ b1,
    const float* __restrict__ g1, const float* __restrict__ be1,
    const float* __restrict__ rm1, const float* __restrict__ rv1,
    const float* __restrict__ W2, const float* __restrict__ b2,
    const float* __restrict__ g2, const float* __restrict__ be2,
    const float* __restrict__ rm2, const float* __restrict__ rv2,
    const float* __restrict__ W3, const float* __restrict__ b3,
    float* __restrict__ out) {
  __shared__ float W1s[64 * 128];
  __shared__ float W2s[128 * 64];
  __shared__ float W3s[64];
  __shared__ float sc1[128], sh1[128], b1s[128];
  __shared__ float sc2[64],  sh2[64],  b2s[64];
  __shared__ float s0[64], s1[128], s2[64];
  int t = threadIdx.x;

  for (int i = t; i < 64 * 128; i += 128) W1s[i] = W1[i];
  for (int i = t; i < 128 * 64; i += 128) W2s[i] = W2[i];
  if (t < 64) W3s[t] = W3[t];
  {
    float iv = rsqrtf(rv1[t] + BN_EPS);
    float sc = g1[t] * iv;
    sc1[t] = sc; sh1[t] = be1[t] - rm1[t] * sc; b1s[t] = b1[t];
  }
  if (t < 64) {
    float iv = rsqrtf(rv2[t] + BN_EPS);
    float sc = g2[t] * iv;
    sc2[t] = sc; sh2[t] = be2[t] - rm2[t] * sc; b2s[t] = b2[t];
  }
  __syncthreads();

  for (int gg = 0; gg < GPB; gg++) {
    int g = blockIdx.x * GPB + gg;
    if (t < 64) s0[t] = hg[(size_t)g * F + t];
    __syncthreads();
    {
      float acc = b1s[t];
      for (int i = 0; i < 64; i++) acc += s0[i] * W1s[i * 128 + t];
      acc = fmaxf(acc, 0.0f);
      s1[t] = acc * sc1[t] + sh1[t];
    }
    __syncthreads();
    if (t < 64) {
      float acc = b2s[t];
      for (int i = 0; i < 128; i++) acc += s1[i] * W2s[i * 64 + t];
      acc = fmaxf(acc, 0.0f);
      s2[t] = acc * sc2[t] + sh2[t];
    }
    __syncthreads();
    if (t < 64) {
      float p = s2[t] * W3s[t];
      for (int off = 32; off > 0; off >>= 1) p += __shfl_down(p, off);
      if (t == 0) out[g] = p + b3[0];
    }
    __syncthreads();
  }
}

// ---------------------------------------------------------------------------
extern "C" void kernel_launch(void* const* d_in, const int* in_sizes, int n_in,
                              void* d_out, int out_size, void* d_ws, size_t ws_size,
                              hipStream_t stream) {
  const float* feats  = (const float*)d_in[0];
  const int*   src    = (const int*)d_in[1];
  const int*   dst    = (const int*)d_in[2];
  const int*   gids   = (const int*)d_in[3];
  const float* Wself  = (const float*)d_in[4];
  const float* Wneigh = (const float*)d_in[5];
  const float* bneigh = (const float*)d_in[6];
  const float* W1  = (const float*)d_in[7];
  const float* b1  = (const float*)d_in[8];
  const float* g1  = (const float*)d_in[9];
  const float* be1 = (const float*)d_in[10];
  const float* rm1 = (const float*)d_in[11];
  const float* rv1 = (const float*)d_in[12];
  const float* W2  = (const float*)d_in[13];
  const float* b2  = (const float*)d_in[14];
  const float* g2  = (const float*)d_in[15];
  const float* be2 = (const float*)d_in[16];
  const float* rm2 = (const float*)d_in[17];
  const float* rv2 = (const float*)d_in[18];
  const float* W3  = (const float*)d_in[19];
  const float* b3  = (const float*)d_in[20];

  // ws layout: mean | rs | bstart | bcnt | hgbits(zeroed) | Ct | pairs | eidx
  float* mean  = (float*)d_ws;                       // N_NODES*F (16B aligned)
  int* rs      = (int*)(mean + (size_t)N_NODES * F); // N_NODES+1
  int* bstart  = rs + (N_NODES + 1);                 // NBUCK+1
  int* bcnt    = bstart + (NBUCK + 1);               // NBUCK
  int* hgbits  = bcnt + NBUCK;                       // N_GRAPHS*F } zeroed
  int* Ct      = hgbits + (size_t)N_GRAPHS * F;      // NBLK*NBUCK
  int* pairs   = Ct + (size_t)NBLK * NBUCK;          // N_EDGES
  int* eidx    = pairs + N_EDGES;                    // N_EDGES

  hipMemsetAsync(hgbits, 0, (size_t)N_GRAPHS * F * sizeof(int), stream);

  chist<<<NBLK, 256, 0, stream>>>(dst, Ct);
  cscan<<<NBUCK, NBLK, 0, stream>>>(Ct, bcnt);
  bscan<<<1, 512, 0, stream>>>(bcnt, bstart);
  cscat<<<NBLK, 256, 0, stream>>>(src, dst, Ct, bstart, pairs);
  place<<<NBUCK, 256, 0, stream>>>(pairs, bstart, rs, eidx);
  gather_mean<<<2048, 256, 0, stream>>>(feats, rs, eidx, mean);
  node_out<<<512, 256, 0, stream>>>(feats, mean, Wself, Wneigh, bneigh,
                                    gids, hgbits);
  mlp<<<N_GRAPHS / GPB, 128, 0, stream>>>((const float*)hgbits,
                                          W1, b1, g1, be1, rm1, rv1,
                                          W2, b2, g2, be2, rm2, rv2, W3, b3,
                                          (float*)d_out);
}

// Round 6
// 279.567 us; speedup vs baseline: 2.4749x; 1.0128x over previous
//
#include <hip/hip_runtime.h>

#define N_NODES  100000
#define N_EDGES  1200000
#define N_GRAPHS 1024
#define F        64
#define BN_EPS   1e-5f
#define NBUCK    ((N_NODES + 255) / 256)     // 391 buckets of 256 node IDs
#define NBLK     512                          // scatter blocks (chunks)
#define CHUNK    ((N_EDGES + NBLK - 1) / NBLK) // 2344 edges per chunk

// ---------------------------------------------------------------------------
// Step 1: per-chunk bucket histogram. LDS counts, plain coalesced stores to
// Ct[block*NBUCK + bucket]. NO global atomics. Also zeroes hgbits (folded
// memset: 256 blocks x 256 threads cover N_GRAPHS*F = 65536 ints).
// ---------------------------------------------------------------------------
__global__ __launch_bounds__(256) void chist(const int* __restrict__ dst,
                                             int* __restrict__ Ct,
                                             int* __restrict__ hgbits) {
  __shared__ int lh[NBUCK];
  int b = blockIdx.x, t = threadIdx.x;
  int zidx = b * 256 + t;
  if (zidx < N_GRAPHS * F) hgbits[zidx] = 0;
  for (int i = t; i < NBUCK; i += 256) lh[i] = 0;
  __syncthreads();
  int e0 = b * CHUNK, e1 = e0 + CHUNK;
  if (e1 > N_EDGES) e1 = N_EDGES;
  for (int e = e0 + t; e < e1; e += 256) atomicAdd(&lh[dst[e] >> 8], 1);
  __syncthreads();
  for (int i = t; i < NBUCK; i += 256) Ct[(size_t)b * NBUCK + i] = lh[i];
}

// ---------------------------------------------------------------------------
// Step 2: per-bucket scan over the NBLK chunk counts -> intra-bucket
// exclusive prefix (in place) + bucket total. One block per bucket.
// ---------------------------------------------------------------------------
__global__ __launch_bounds__(NBLK) void cscan(int* __restrict__ Ct,
                                              int* __restrict__ bcnt) {
  __shared__ int s[NBLK];
  int i = blockIdx.x, t = threadIdx.x;
  int v = Ct[(size_t)t * NBUCK + i];
  s[t] = v;
  __syncthreads();
  for (int off = 1; off < NBLK; off <<= 1) {
    int u = (t >= off) ? s[t - off] : 0;
    __syncthreads();
    s[t] += u;
    __syncthreads();
  }
  Ct[(size_t)t * NBUCK + i] = s[t] - v;     // exclusive prefix within bucket
  if (t == NBLK - 1) bcnt[i] = s[NBLK - 1]; // bucket total
}

// ---------------------------------------------------------------------------
// Step 3: scan 391 bucket totals -> bstart. One block.
// ---------------------------------------------------------------------------
__global__ __launch_bounds__(512) void bscan(const int* __restrict__ bcnt,
                                             int* __restrict__ bstart) {
  __shared__ int s[512];
  int t = threadIdx.x;
  int v = (t < NBUCK) ? bcnt[t] : 0;
  s[t] = v;
  __syncthreads();
  for (int off = 1; off < 512; off <<= 1) {
    int u = (t >= off) ? s[t - off] : 0;
    __syncthreads();
    s[t] += u;
    __syncthreads();
  }
  if (t < NBUCK) bstart[t] = s[t] - v;
  if (t == 0) bstart[NBUCK] = N_EDGES;
}

// ---------------------------------------------------------------------------
// Step 4: deterministic scatter. Block b seeds LDS cursors from its reserved
// ranges (bstart + intra-bucket prefix), then places packed
// (local_dst<<24 | src) with LDS atomics only. Disjoint output sub-ranges.
// ---------------------------------------------------------------------------
__global__ __launch_bounds__(256) void cscat(const int* __restrict__ src,
                                             const int* __restrict__ dst,
                                             const int* __restrict__ Ct,
                                             const int* __restrict__ bstart,
                                             int* __restrict__ pairs) {
  __shared__ int cur[NBUCK];
  int b = blockIdx.x, t = threadIdx.x;
  for (int i = t; i < NBUCK; i += 256)
    cur[i] = bstart[i] + Ct[(size_t)b * NBUCK + i];
  __syncthreads();
  int e0 = b * CHUNK, e1 = e0 + CHUNK;
  if (e1 > N_EDGES) e1 = N_EDGES;
  for (int e = e0 + t; e < e1; e += 256) {
    int d = dst[e];
    int pos = atomicAdd(&cur[d >> 8], 1);
    pairs[pos] = (int)((((unsigned)d & 255u) << 24) | (unsigned)src[e]);
  }
}

// ---------------------------------------------------------------------------
// Step 5: per-bucket place. LDS hist of local dst, LDS scan (produces rs),
// LDS-cursor scatter into the block-owned contiguous eidx region.
// ---------------------------------------------------------------------------
__global__ __launch_bounds__(256) void place(const int* __restrict__ pairs,
                                             const int* __restrict__ bstart,
                                             int* __restrict__ rs,
                                             int* __restrict__ eidx) {
  __shared__ int lh[256];
  __shared__ int cur[256];
  int b = blockIdx.x, t = threadIdx.x;
  int nb0 = b << 8;
  int r0 = bstart[b], r1 = bstart[b + 1];

  lh[t] = 0;
  __syncthreads();
  for (int e = r0 + t; e < r1; e += 256)
    atomicAdd(&lh[((unsigned)pairs[e]) >> 24], 1);
  __syncthreads();

  int v = lh[t];
  cur[t] = v;
  __syncthreads();
  for (int off = 1; off < 256; off <<= 1) {
    int u = (t >= off) ? cur[t - off] : 0;
    __syncthreads();
    cur[t] += u;
    __syncthreads();
  }
  int excl = cur[t] - v;
  int node = nb0 + t;
  if (node < N_NODES) rs[node] = r0 + excl;
  if (b == 0 && t == 0) rs[N_NODES] = N_EDGES;
  __syncthreads();
  cur[t] = r0 + excl;
  __syncthreads();

  for (int e = r0 + t; e < r1; e += 256) {
    unsigned p = (unsigned)pairs[e];
    int pos = atomicAdd(&cur[p >> 24], 1);
    eidx[pos] = (int)(p & 0xFFFFFFu);
  }
}

// ---------------------------------------------------------------------------
// Neighbor-mean gather. lane = 16*sub + f4: each float4 load covers 4
// neighbor rows (1KB/wave). Low VGPR -> high occupancy.
// ---------------------------------------------------------------------------
__global__ __launch_bounds__(256) void gather_mean(
    const float* __restrict__ feats, const int* __restrict__ rs,
    const int* __restrict__ eidx, float* __restrict__ mean) {
  int lane = threadIdx.x & 63;
  int wid  = (blockIdx.x * blockDim.x + threadIdx.x) >> 6;
  const int NW = (2048 * 256) >> 6;                 // 8192 waves
  const int per = (N_NODES + NW - 1) / NW;          // 13 nodes/wave
  int n0 = wid * per;
  int n1 = n0 + per; if (n1 > N_NODES) n1 = N_NODES;
  int fl  = lane & 15;
  int sub = lane >> 4;

  for (int n = n0; n < n1; n++) {
    int r0 = rs[n], r1 = rs[n + 1];
    float sx = 0.f, sy = 0.f, sz = 0.f, sw = 0.f;
    for (int base = r0; base < r1; base += 64) {
      int m = r1 - base; if (m > 64) m = 64;
      int myid = (lane < m) ? eidx[base + lane] : 0;
      for (int j = 0; j < m; j += 4) {
        int sid = __shfl(myid, j + sub);
        const float4 v =
            *(const float4*)(feats + (size_t)sid * F + 4 * fl);
        if (j + sub < m) { sx += v.x; sy += v.y; sz += v.z; sw += v.w; }
      }
    }
    sx += __shfl_xor(sx, 16); sy += __shfl_xor(sy, 16);
    sz += __shfl_xor(sz, 16); sw += __shfl_xor(sw, 16);
    sx += __shfl_xor(sx, 32); sy += __shfl_xor(sy, 32);
    sz += __shfl_xor(sz, 32); sw += __shfl_xor(sw, 32);
    float inv = 1.0f / fmaxf((float)(r1 - r0), 1.0f);
    if (sub == 0) {
      float4 mv = {sx * inv, sy * inv, sz * inv, sw * inv};
      *(float4*)(mean + (size_t)n * F + 4 * fl) = mv;
    }
  }
}

// ---------------------------------------------------------------------------
// SAGE update + ReLU + per-graph max, v2.
// One wave per block, launch_bounds(64,1) -> 512-VGPR budget. Weight columns
// pinned in 128 VGPRs via identity-shuffle (compiler cannot sink/remat loads
// past ds_bpermute). Per-node feats/mean rows are WAVE-UNIFORM -> compiler
// emits s_load (SMEM pipe, off-VALU): inner loop is 128 pure v_fmac_f32.
// ---------------------------------------------------------------------------
__global__ __launch_bounds__(64, 1) void node_out(
    const float* __restrict__ feats, const float* __restrict__ mean,
    const float* __restrict__ Wself, const float* __restrict__ Wneigh,
    const float* __restrict__ bneigh, const int* __restrict__ gids,
    int* __restrict__ hgbits) {
  int lane = threadIdx.x;
  int wid  = blockIdx.x;
  const int NW = 2048;
  const int per = (N_NODES + NW - 1) / NW;          // 49 nodes/wave
  int n0 = wid * per;
  int n1 = n0 + per; if (n1 > N_NODES) n1 = N_NODES;
  if (n0 >= n1) return;

  float wsv[F], wnv[F];
#pragma unroll
  for (int i = 0; i < F; i++) {
    wsv[i] = Wself[i * F + lane];
    wnv[i] = Wneigh[i * F + lane];
  }
  // identity shuffle: pins the 128 weight values in VGPRs (opaque to remat)
#pragma unroll
  for (int i = 0; i < F; i++) {
    wsv[i] = __shfl(wsv[i], lane);
    wnv[i] = __shfl(wnv[i], lane);
  }
  float bias = bneigh[lane];

  int curg = gids[n0];
  float gmax = 0.0f;
  for (int n = n0; n < n1; n++) {
    int g = gids[n];                                // uniform scalar load
    if (g != curg) {
      atomicMax(&hgbits[(size_t)curg * F + lane], __float_as_int(gmax));
      curg = g; gmax = 0.0f;
    }
    const float* fr = feats + (size_t)n * F;        // wave-uniform rows
    const float* mr = mean  + (size_t)n * F;
    float acc = bias;
#pragma unroll
    for (int i = 0; i < F; i++) {
      acc += fr[i] * wsv[i];                        // s_load * v_fmac
      acc += mr[i] * wnv[i];
    }
    gmax = fmaxf(gmax, fmaxf(acc, 0.0f));
  }
  atomicMax(&hgbits[(size_t)curg * F + lane], __float_as_int(gmax));
}

// ---------------------------------------------------------------------------
// MLP head: weights staged in LDS once, 8 graphs per block.
// ---------------------------------------------------------------------------
#define GPB 8
__global__ __launch_bounds__(128) void mlp(
    const float* __restrict__ hg,
    const float* __restrict__ W1, const float* __restrict__ b1,
    const float* __restrict__ g1, const float* __restrict__ be1,
    const float* __restrict__ rm1, const float* __restrict__ rv1,
    const float* __restrict__ W2, const float* __restrict__ b2,
    const float* __restrict__ g2, const float* __restrict__ be2,
    const float* __restrict__ rm2, const float* __restrict__ rv2,
    const float* __restrict__ W3, const float* __restrict__ b3,
    float* __restrict__ out) {
  __shared__ float W1s[64 * 128];
  __shared__ float W2s[128 * 64];
  __shared__ float W3s[64];
  __shared__ float sc1[128], sh1[128], b1s[128];
  __shared__ float sc2[64],  sh2[64],  b2s[64];
  __shared__ float s0[64], s1[128], s2[64];
  int t = threadIdx.x;

  for (int i = t; i < 64 * 128; i += 128) W1s[i] = W1[i];
  for (int i = t; i < 128 * 64; i += 128) W2s[i] = W2[i];
  if (t < 64) W3s[t] = W3[t];
  {
    float iv = rsqrtf(rv1[t] + BN_EPS);
    float sc = g1[t] * iv;
    sc1[t] = sc; sh1[t] = be1[t] - rm1[t] * sc; b1s[t] = b1[t];
  }
  if (t < 64) {
    float iv = rsqrtf(rv2[t] + BN_EPS);
    float sc = g2[t] * iv;
    sc2[t] = sc; sh2[t] = be2[t] - rm2[t] * sc; b2s[t] = b2[t];
  }
  __syncthreads();

  for (int gg = 0; gg < GPB; gg++) {
    int g = blockIdx.x * GPB + gg;
    if (t < 64) s0[t] = hg[(size_t)g * F + t];
    __syncthreads();
    {
      float acc = b1s[t];
      for (int i = 0; i < 64; i++) acc += s0[i] * W1s[i * 128 + t];
      acc = fmaxf(acc, 0.0f);
      s1[t] = acc * sc1[t] + sh1[t];
    }
    __syncthreads();
    if (t < 64) {
      float acc = b2s[t];
      for (int i = 0; i < 128; i++) acc += s1[i] * W2s[i * 64 + t];
      acc = fmaxf(acc, 0.0f);
      s2[t] = acc * sc2[t] + sh2[t];
    }
    __syncthreads();
    if (t < 64) {
      float p = s2[t] * W3s[t];
      for (int off = 32; off > 0; off >>= 1) p += __shfl_down(p, off);
      if (t == 0) out[g] = p + b3[0];
    }
    __syncthreads();
  }
}

// ---------------------------------------------------------------------------
extern "C" void kernel_launch(void* const* d_in, const int* in_sizes, int n_in,
                              void* d_out, int out_size, void* d_ws, size_t ws_size,
                              hipStream_t stream) {
  const float* feats  = (const float*)d_in[0];
  const int*   src    = (const int*)d_in[1];
  const int*   dst    = (const int*)d_in[2];
  const int*   gids   = (const int*)d_in[3];
  const float* Wself  = (const float*)d_in[4];
  const float* Wneigh = (const float*)d_in[5];
  const float* bneigh = (const float*)d_in[6];
  const float* W1  = (const float*)d_in[7];
  const float* b1  = (const float*)d_in[8];
  const float* g1  = (const float*)d_in[9];
  const float* be1 = (const float*)d_in[10];
  const float* rm1 = (const float*)d_in[11];
  const float* rv1 = (const float*)d_in[12];
  const float* W2  = (const float*)d_in[13];
  const float* b2  = (const float*)d_in[14];
  const float* g2  = (const float*)d_in[15];
  const float* be2 = (const float*)d_in[16];
  const float* rm2 = (const float*)d_in[17];
  const float* rv2 = (const float*)d_in[18];
  const float* W3  = (const float*)d_in[19];
  const float* b3  = (const float*)d_in[20];

  // ws layout: mean | rs | bstart | bcnt | hgbits | Ct | pairs | eidx
  float* mean  = (float*)d_ws;                       // N_NODES*F (16B aligned)
  int* rs      = (int*)(mean + (size_t)N_NODES * F); // N_NODES+1
  int* bstart  = rs + (N_NODES + 1);                 // NBUCK+1
  int* bcnt    = bstart + (NBUCK + 1);               // NBUCK
  int* hgbits  = bcnt + NBUCK;                       // N_GRAPHS*F (zeroed in chist)
  int* Ct      = hgbits + (size_t)N_GRAPHS * F;      // NBLK*NBUCK
  int* pairs   = Ct + (size_t)NBLK * NBUCK;          // N_EDGES
  int* eidx    = pairs + N_EDGES;                    // N_EDGES

  chist<<<NBLK, 256, 0, stream>>>(dst, Ct, hgbits);
  cscan<<<NBUCK, NBLK, 0, stream>>>(Ct, bcnt);
  bscan<<<1, 512, 0, stream>>>(bcnt, bstart);
  cscat<<<NBLK, 256, 0, stream>>>(src, dst, Ct, bstart, pairs);
  place<<<NBUCK, 256, 0, stream>>>(pairs, bstart, rs, eidx);
  gather_mean<<<2048, 256, 0, stream>>>(feats, rs, eidx, mean);
  node_out<<<2048, 64, 0, stream>>>(feats, mean, Wself, Wneigh, bneigh,
                                    gids, hgbits);
  mlp<<<N_GRAPHS / GPB, 128, 0, stream>>>((const float*)hgbits,
                                          W1, b1, g1, be1, rm1, rv1,
                                          W2, b2, g2, be2, rm2, rv2, W3, b3,
                                          (float*)d_out);
}

// Round 7
// 240.754 us; speedup vs baseline: 2.8739x; 1.1612x over previous
//
#include <hip/hip_runtime.h>
#include <hip/hip_fp16.h>

#define N_NODES  100000
#define N_EDGES  1200000
#define N_GRAPHS 1024
#define F        64
#define BN_EPS   1e-5f
#define NBUCK    ((N_NODES + 255) / 256)     // 391 buckets of 256 node IDs
#define NBLK     512                          // scatter blocks (chunks)
#define CHUNK    ((N_EDGES + NBLK - 1) / NBLK) // 2344 edges per chunk
#define MT       128                          // GEMM nodes per block

// ---------------------------------------------------------------------------
// CSR build (unchanged, proven): chist -> cscan -> bscan -> cscat -> place
// ---------------------------------------------------------------------------
__global__ __launch_bounds__(256) void chist(const int* __restrict__ dst,
                                             int* __restrict__ Ct,
                                             int* __restrict__ hgbits) {
  __shared__ int lh[NBUCK];
  int b = blockIdx.x, t = threadIdx.x;
  int zidx = b * 256 + t;
  if (zidx < N_GRAPHS * F) hgbits[zidx] = 0;
  for (int i = t; i < NBUCK; i += 256) lh[i] = 0;
  __syncthreads();
  int e0 = b * CHUNK, e1 = e0 + CHUNK;
  if (e1 > N_EDGES) e1 = N_EDGES;
  for (int e = e0 + t; e < e1; e += 256) atomicAdd(&lh[dst[e] >> 8], 1);
  __syncthreads();
  for (int i = t; i < NBUCK; i += 256) Ct[(size_t)b * NBUCK + i] = lh[i];
}

__global__ __launch_bounds__(NBLK) void cscan(int* __restrict__ Ct,
                                              int* __restrict__ bcnt) {
  __shared__ int s[NBLK];
  int i = blockIdx.x, t = threadIdx.x;
  int v = Ct[(size_t)t * NBUCK + i];
  s[t] = v;
  __syncthreads();
  for (int off = 1; off < NBLK; off <<= 1) {
    int u = (t >= off) ? s[t - off] : 0;
    __syncthreads();
    s[t] += u;
    __syncthreads();
  }
  Ct[(size_t)t * NBUCK + i] = s[t] - v;
  if (t == NBLK - 1) bcnt[i] = s[NBLK - 1];
}

__global__ __launch_bounds__(512) void bscan(const int* __restrict__ bcnt,
                                             int* __restrict__ bstart) {
  __shared__ int s[512];
  int t = threadIdx.x;
  int v = (t < NBUCK) ? bcnt[t] : 0;
  s[t] = v;
  __syncthreads();
  for (int off = 1; off < 512; off <<= 1) {
    int u = (t >= off) ? s[t - off] : 0;
    __syncthreads();
    s[t] += u;
    __syncthreads();
  }
  if (t < NBUCK) bstart[t] = s[t] - v;
  if (t == 0) bstart[NBUCK] = N_EDGES;
}

__global__ __launch_bounds__(256) void cscat(const int* __restrict__ src,
                                             const int* __restrict__ dst,
                                             const int* __restrict__ Ct,
                                             const int* __restrict__ bstart,
                                             int* __restrict__ pairs) {
  __shared__ int cur[NBUCK];
  int b = blockIdx.x, t = threadIdx.x;
  for (int i = t; i < NBUCK; i += 256)
    cur[i] = bstart[i] + Ct[(size_t)b * NBUCK + i];
  __syncthreads();
  int e0 = b * CHUNK, e1 = e0 + CHUNK;
  if (e1 > N_EDGES) e1 = N_EDGES;
  for (int e = e0 + t; e < e1; e += 256) {
    int d = dst[e];
    int pos = atomicAdd(&cur[d >> 8], 1);
    pairs[pos] = (int)((((unsigned)d & 255u) << 24) | (unsigned)src[e]);
  }
}

__global__ __launch_bounds__(256) void place(const int* __restrict__ pairs,
                                             const int* __restrict__ bstart,
                                             int* __restrict__ rs,
                                             int* __restrict__ eidx) {
  __shared__ int lh[256];
  __shared__ int cur[256];
  int b = blockIdx.x, t = threadIdx.x;
  int nb0 = b << 8;
  int r0 = bstart[b], r1 = bstart[b + 1];

  lh[t] = 0;
  __syncthreads();
  for (int e = r0 + t; e < r1; e += 256)
    atomicAdd(&lh[((unsigned)pairs[e]) >> 24], 1);
  __syncthreads();

  int v = lh[t];
  cur[t] = v;
  __syncthreads();
  for (int off = 1; off < 256; off <<= 1) {
    int u = (t >= off) ? cur[t - off] : 0;
    __syncthreads();
    cur[t] += u;
    __syncthreads();
  }
  int excl = cur[t] - v;
  int node = nb0 + t;
  if (node < N_NODES) rs[node] = r0 + excl;
  if (b == 0 && t == 0) rs[N_NODES] = N_EDGES;
  __syncthreads();
  cur[t] = r0 + excl;
  __syncthreads();

  for (int e = r0 + t; e < r1; e += 256) {
    unsigned p = (unsigned)pairs[e];
    int pos = atomicAdd(&cur[p >> 24], 1);
    eidx[pos] = (int)(p & 0xFFFFFFu);
  }
}

// ---------------------------------------------------------------------------
// Dense GEMM: UZ[n][0:64] = feats[n] @ Wself, UZ[n][64:128] = feats[n] @ Wneigh
// (fp16 output). LDS: A-tile 128x65 fp32 + W 64x128 fp32 (66 KB).
// Wave w: half=w&1 (U or Z), nodes (w>>1)*64 .. +63. Thread (nq=lane>>2,
// jq=lane&3): 4 nodes x 16 outputs in 64 VGPR acc. W reads are 16-lane
// broadcasts; A reads 2-way bank alias (free). FMA-bound.
// ---------------------------------------------------------------------------
__global__ __launch_bounds__(256) void gemm_uz(
    const float* __restrict__ feats, const float* __restrict__ Wself,
    const float* __restrict__ Wneigh, __half* __restrict__ UZh) {
  __shared__ float As[MT * 65];
  __shared__ float Ws[64 * 128];
  int t = threadIdx.x;
  int mbase = blockIdx.x * MT;

  for (int i = t; i < 64 * 128; i += 256) {
    int k = i >> 7, j = i & 127;
    Ws[i] = (j < 64) ? Wself[k * 64 + j] : Wneigh[k * 64 + (j - 64)];
  }
#pragma unroll
  for (int s = 0; s < 8; s++) {
    int idx = (s * 256 + t) * 4;
    int m = idx >> 6, k = idx & 63;
    int gm = mbase + m;
    float4 v = (gm < N_NODES) ? *(const float4*)(feats + (size_t)gm * F + k)
                              : make_float4(0.f, 0.f, 0.f, 0.f);
    float* d = As + m * 65 + k;
    d[0] = v.x; d[1] = v.y; d[2] = v.z; d[3] = v.w;
  }
  __syncthreads();

  int wave = t >> 6, lane = t & 63;
  int jq = lane & 3, nq = lane >> 2;
  int half = wave & 1;
  int mb = (wave >> 1) * 64 + 4 * nq;          // 4 nodes: mb..mb+3
  int joff = half * 64 + jq * 16;              // 16 outputs: joff..joff+15

  float acc[4][16];
#pragma unroll
  for (int i = 0; i < 4; i++)
#pragma unroll
    for (int c = 0; c < 16; c++) acc[i][c] = 0.f;

#pragma unroll 4
  for (int k = 0; k < 64; k++) {
    float a0 = As[(mb + 0) * 65 + k];
    float a1 = As[(mb + 1) * 65 + k];
    float a2 = As[(mb + 2) * 65 + k];
    float a3 = As[(mb + 3) * 65 + k];
    const float* wr = Ws + k * 128 + joff;
#pragma unroll
    for (int c = 0; c < 16; c++) {
      float w = wr[c];
      acc[0][c] += a0 * w;
      acc[1][c] += a1 * w;
      acc[2][c] += a2 * w;
      acc[3][c] += a3 * w;
    }
  }

#pragma unroll
  for (int i = 0; i < 4; i++) {
    int gm = mbase + mb + i;
    if (gm < N_NODES) {
#pragma unroll
      for (int c4 = 0; c4 < 4; c4++) {
        union { __half h[4]; uint2 u; } pk;
        pk.h[0] = __float2half_rn(acc[i][c4 * 4 + 0]);
        pk.h[1] = __float2half_rn(acc[i][c4 * 4 + 1]);
        pk.h[2] = __float2half_rn(acc[i][c4 * 4 + 2]);
        pk.h[3] = __float2half_rn(acc[i][c4 * 4 + 3]);
        *(uint2*)(UZh + (size_t)gm * 128 + joff + c4 * 4) = pk.u;
      }
    }
  }
}

// ---------------------------------------------------------------------------
// Fused gather + SAGE update + ReLU + per-graph max readout.
// Aggregates Z (fp16) rows; h = relu(U + Zmean + b) computed in-wave;
// per-(wave,graph) atomicMax flush. lane = 16*sub + fl: each uint2 load
// covers 4 neighbor Z-rows (512B/instr).
// ---------------------------------------------------------------------------
__global__ __launch_bounds__(256) void gather_h(
    const __half* __restrict__ UZh, const int* __restrict__ rs,
    const int* __restrict__ eidx, const float* __restrict__ bneigh,
    const int* __restrict__ gids, int* __restrict__ hgbits) {
  int lane = threadIdx.x & 63;
  int wid  = (blockIdx.x * blockDim.x + threadIdx.x) >> 6;
  const int NW = (2048 * 256) >> 6;                 // 8192 waves
  const int per = (N_NODES + NW - 1) / NW;          // 13 nodes/wave
  int n0 = wid * per;
  int n1 = n0 + per; if (n1 > N_NODES) n1 = N_NODES;
  if (n0 >= n1) return;
  int fl  = lane & 15;
  int sub = lane >> 4;
  float4 b4 = *(const float4*)(bneigh + 4 * fl);

  int curg = gids[n0];
  float4 gmax = {0.f, 0.f, 0.f, 0.f};

  for (int n = n0; n < n1; n++) {
    int r0 = rs[n], r1 = rs[n + 1];
    float sx = 0.f, sy = 0.f, sz = 0.f, sw = 0.f;
    for (int base = r0; base < r1; base += 64) {
      int m = r1 - base; if (m > 64) m = 64;
      int myid = (lane < m) ? eidx[base + lane] : 0;
      for (int j = 0; j < m; j += 4) {
        int sid = __shfl(myid, j + sub);
        uint2 zr = *(const uint2*)(UZh + (size_t)sid * 128 + 64 + 4 * fl);
        __half2 z0 = *(__half2*)&zr.x;
        __half2 z1 = *(__half2*)&zr.y;
        float2 f0 = __half22float2(z0);
        float2 f1 = __half22float2(z1);
        if (j + sub < m) { sx += f0.x; sy += f0.y; sz += f1.x; sw += f1.y; }
      }
    }
    sx += __shfl_xor(sx, 16); sy += __shfl_xor(sy, 16);
    sz += __shfl_xor(sz, 16); sw += __shfl_xor(sw, 16);
    sx += __shfl_xor(sx, 32); sy += __shfl_xor(sy, 32);
    sz += __shfl_xor(sz, 32); sw += __shfl_xor(sw, 32);
    float inv = 1.0f / fmaxf((float)(r1 - r0), 1.0f);

    int g = gids[n];                                // wave-uniform
    if (g != curg) {
      if (sub == 0) {
        int* hp = hgbits + (size_t)curg * F + 4 * fl;
        atomicMax(hp + 0, __float_as_int(gmax.x));
        atomicMax(hp + 1, __float_as_int(gmax.y));
        atomicMax(hp + 2, __float_as_int(gmax.z));
        atomicMax(hp + 3, __float_as_int(gmax.w));
      }
      curg = g; gmax = make_float4(0.f, 0.f, 0.f, 0.f);
    }

    uint2 ur = *(const uint2*)(UZh + (size_t)n * 128 + 4 * fl);
    __half2 u0 = *(__half2*)&ur.x;
    __half2 u1 = *(__half2*)&ur.y;
    float2 uf0 = __half22float2(u0);
    float2 uf1 = __half22float2(u1);
    float hx = fmaxf(uf0.x + sx * inv + b4.x, 0.f);
    float hy = fmaxf(uf0.y + sy * inv + b4.y, 0.f);
    float hz = fmaxf(uf1.x + sz * inv + b4.z, 0.f);
    float hw = fmaxf(uf1.y + sw * inv + b4.w, 0.f);
    gmax.x = fmaxf(gmax.x, hx);
    gmax.y = fmaxf(gmax.y, hy);
    gmax.z = fmaxf(gmax.z, hz);
    gmax.w = fmaxf(gmax.w, hw);
  }
  if (sub == 0) {
    int* hp = hgbits + (size_t)curg * F + 4 * fl;
    atomicMax(hp + 0, __float_as_int(gmax.x));
    atomicMax(hp + 1, __float_as_int(gmax.y));
    atomicMax(hp + 2, __float_as_int(gmax.z));
    atomicMax(hp + 3, __float_as_int(gmax.w));
  }
}

// ---------------------------------------------------------------------------
// MLP head: weights staged in LDS once, 8 graphs per block.
// ---------------------------------------------------------------------------
#define GPB 8
__global__ __launch_bounds__(128) void mlp(
    const float* __restrict__ hg,
    const float* __restrict__ W1, const float* __restrict__ b1,
    const float* __restrict__ g1, const float* __restrict__ be1,
    const float* __restrict__ rm1, const float* __restrict__ rv1,
    const float* __restrict__ W2, const float* __restrict__ b2,
    const float* __restrict__ g2, const float* __restrict__ be2,
    const float* __restrict__ rm2, const float* __restrict__ rv2,
    const float* __restrict__ W3, const float* __restrict__ b3,
    float* __restrict__ out) {
  __shared__ float W1s[64 * 128];
  __shared__ float W2s[128 * 64];
  __shared__ float W3s[64];
  __shared__ float sc1[128], sh1[128], b1s[128];
  __shared__ float sc2[64],  sh2[64],  b2s[64];
  __shared__ float s0[64], s1[128], s2[64];
  int t = threadIdx.x;

  for (int i = t; i < 64 * 128; i += 128) W1s[i] = W1[i];
  for (int i = t; i < 128 * 64; i += 128) W2s[i] = W2[i];
  if (t < 64) W3s[t] = W3[t];
  {
    float iv = rsqrtf(rv1[t] + BN_EPS);
    float sc = g1[t] * iv;
    sc1[t] = sc; sh1[t] = be1[t] - rm1[t] * sc; b1s[t] = b1[t];
  }
  if (t < 64) {
    float iv = rsqrtf(rv2[t] + BN_EPS);
    float sc = g2[t] * iv;
    sc2[t] = sc; sh2[t] = be2[t] - rm2[t] * sc; b2s[t] = b2[t];
  }
  __syncthreads();

  for (int gg = 0; gg < GPB; gg++) {
    int g = blockIdx.x * GPB + gg;
    if (t < 64) s0[t] = hg[(size_t)g * F + t];
    __syncthreads();
    {
      float acc = b1s[t];
      for (int i = 0; i < 64; i++) acc += s0[i] * W1s[i * 128 + t];
      acc = fmaxf(acc, 0.0f);
      s1[t] = acc * sc1[t] + sh1[t];
    }
    __syncthreads();
    if (t < 64) {
      float acc = b2s[t];
      for (int i = 0; i < 128; i++) acc += s1[i] * W2s[i * 64 + t];
      acc = fmaxf(acc, 0.0f);
      s2[t] = acc * sc2[t] + sh2[t];
    }
    __syncthreads();
    if (t < 64) {
      float p = s2[t] * W3s[t];
      for (int off = 32; off > 0; off >>= 1) p += __shfl_down(p, off);
      if (t == 0) out[g] = p + b3[0];
    }
    __syncthreads();
  }
}

// ---------------------------------------------------------------------------
extern "C" void kernel_launch(void* const* d_in, const int* in_sizes, int n_in,
                              void* d_out, int out_size, void* d_ws, size_t ws_size,
                              hipStream_t stream) {
  const float* feats  = (const float*)d_in[0];
  const int*   src    = (const int*)d_in[1];
  const int*   dst    = (const int*)d_in[2];
  const int*   gids   = (const int*)d_in[3];
  const float* Wself  = (const float*)d_in[4];
  const float* Wneigh = (const float*)d_in[5];
  const float* bneigh = (const float*)d_in[6];
  const float* W1  = (const float*)d_in[7];
  const float* b1  = (const float*)d_in[8];
  const float* g1  = (const float*)d_in[9];
  const float* be1 = (const float*)d_in[10];
  const float* rm1 = (const float*)d_in[11];
  const float* rv1 = (const float*)d_in[12];
  const float* W2  = (const float*)d_in[13];
  const float* b2  = (const float*)d_in[14];
  const float* g2  = (const float*)d_in[15];
  const float* be2 = (const float*)d_in[16];
  const float* rm2 = (const float*)d_in[17];
  const float* rv2 = (const float*)d_in[18];
  const float* W3  = (const float*)d_in[19];
  const float* b3  = (const float*)d_in[20];

  // ws layout: UZh (fp16, 25.6MB -- same footprint as old fp32 `mean`) |
  //            rs | bstart | bcnt | hgbits | Ct | pairs | eidx
  __half* UZh  = (__half*)d_ws;                      // N_NODES*128 halves
  int* rs      = (int*)(UZh + (size_t)N_NODES * 128);// N_NODES+1
  int* bstart  = rs + (N_NODES + 1);                 // NBUCK+1
  int* bcnt    = bstart + (NBUCK + 1);               // NBUCK
  int* hgbits  = bcnt + NBUCK;                       // N_GRAPHS*F (zeroed in chist)
  int* Ct      = hgbits + (size_t)N_GRAPHS * F;      // NBLK*NBUCK
  int* pairs   = Ct + (size_t)NBLK * NBUCK;          // N_EDGES
  int* eidx    = pairs + N_EDGES;                    // N_EDGES

  chist<<<NBLK, 256, 0, stream>>>(dst, Ct, hgbits);
  cscan<<<NBUCK, NBLK, 0, stream>>>(Ct, bcnt);
  bscan<<<1, 512, 0, stream>>>(bcnt, bstart);
  cscat<<<NBLK, 256, 0, stream>>>(src, dst, Ct, bstart, pairs);
  gemm_uz<<<(N_NODES + MT - 1) / MT, 256, 0, stream>>>(feats, Wself, Wneigh, UZh);
  place<<<NBUCK, 256, 0, stream>>>(pairs, bstart, rs, eidx);
  gather_h<<<2048, 256, 0, stream>>>(UZh, rs, eidx, bneigh, gids, hgbits);
  mlp<<<N_GRAPHS / GPB, 128, 0, stream>>>((const float*)hgbits,
                                          W1, b1, g1, be1, rm1, rv1,
                                          W2, b2, g2, be2, rm2, rv2, W3, b3,
                                          (float*)d_out);
}

// Round 8
// 230.079 us; speedup vs baseline: 3.0073x; 1.0464x over previous
//
#include <hip/hip_runtime.h>
#include <hip/hip_fp16.h>

#define N_NODES  100000
#define N_EDGES  1200000
#define N_GRAPHS 1024
#define F        64
#define BN_EPS   1e-5f
#define NBUCK    ((N_NODES + 255) / 256)     // 391 buckets of 256 node IDs
#define NBLK     512                          // scatter blocks (chunks)
#define CHUNK    ((N_EDGES + NBLK - 1) / NBLK) // 2344 edges per chunk
#define MT       128                          // GEMM nodes per block

// ---------------------------------------------------------------------------
// CSR build (unchanged, proven): chist -> cscan -> bscan -> cscat -> place
// ---------------------------------------------------------------------------
__global__ __launch_bounds__(256) void chist(const int* __restrict__ dst,
                                             int* __restrict__ Ct,
                                             int* __restrict__ hgbits) {
  __shared__ int lh[NBUCK];
  int b = blockIdx.x, t = threadIdx.x;
  int zidx = b * 256 + t;
  if (zidx < N_GRAPHS * F) hgbits[zidx] = 0;
  for (int i = t; i < NBUCK; i += 256) lh[i] = 0;
  __syncthreads();
  int e0 = b * CHUNK, e1 = e0 + CHUNK;
  if (e1 > N_EDGES) e1 = N_EDGES;
  for (int e = e0 + t; e < e1; e += 256) atomicAdd(&lh[dst[e] >> 8], 1);
  __syncthreads();
  for (int i = t; i < NBUCK; i += 256) Ct[(size_t)b * NBUCK + i] = lh[i];
}

__global__ __launch_bounds__(NBLK) void cscan(int* __restrict__ Ct,
                                              int* __restrict__ bcnt) {
  __shared__ int s[NBLK];
  int i = blockIdx.x, t = threadIdx.x;
  int v = Ct[(size_t)t * NBUCK + i];
  s[t] = v;
  __syncthreads();
  for (int off = 1; off < NBLK; off <<= 1) {
    int u = (t >= off) ? s[t - off] : 0;
    __syncthreads();
    s[t] += u;
    __syncthreads();
  }
  Ct[(size_t)t * NBUCK + i] = s[t] - v;
  if (t == NBLK - 1) bcnt[i] = s[NBLK - 1];
}

__global__ __launch_bounds__(512) void bscan(const int* __restrict__ bcnt,
                                             int* __restrict__ bstart) {
  __shared__ int s[512];
  int t = threadIdx.x;
  int v = (t < NBUCK) ? bcnt[t] : 0;
  s[t] = v;
  __syncthreads();
  for (int off = 1; off < 512; off <<= 1) {
    int u = (t >= off) ? s[t - off] : 0;
    __syncthreads();
    s[t] += u;
    __syncthreads();
  }
  if (t < NBUCK) bstart[t] = s[t] - v;
  if (t == 0) bstart[NBUCK] = N_EDGES;
}

__global__ __launch_bounds__(256) void cscat(const int* __restrict__ src,
                                             const int* __restrict__ dst,
                                             const int* __restrict__ Ct,
                                             const int* __restrict__ bstart,
                                             int* __restrict__ pairs) {
  __shared__ int cur[NBUCK];
  int b = blockIdx.x, t = threadIdx.x;
  for (int i = t; i < NBUCK; i += 256)
    cur[i] = bstart[i] + Ct[(size_t)b * NBUCK + i];
  __syncthreads();
  int e0 = b * CHUNK, e1 = e0 + CHUNK;
  if (e1 > N_EDGES) e1 = N_EDGES;
  for (int e = e0 + t; e < e1; e += 256) {
    int d = dst[e];
    int pos = atomicAdd(&cur[d >> 8], 1);
    pairs[pos] = (int)((((unsigned)d & 255u) << 24) | (unsigned)src[e]);
  }
}

__global__ __launch_bounds__(256) void place(const int* __restrict__ pairs,
                                             const int* __restrict__ bstart,
                                             int* __restrict__ rs,
                                             int* __restrict__ eidx) {
  __shared__ int lh[256];
  __shared__ int cur[256];
  int b = blockIdx.x, t = threadIdx.x;
  int nb0 = b << 8;
  int r0 = bstart[b], r1 = bstart[b + 1];

  lh[t] = 0;
  __syncthreads();
  for (int e = r0 + t; e < r1; e += 256)
    atomicAdd(&lh[((unsigned)pairs[e]) >> 24], 1);
  __syncthreads();

  int v = lh[t];
  cur[t] = v;
  __syncthreads();
  for (int off = 1; off < 256; off <<= 1) {
    int u = (t >= off) ? cur[t - off] : 0;
    __syncthreads();
    cur[t] += u;
    __syncthreads();
  }
  int excl = cur[t] - v;
  int node = nb0 + t;
  if (node < N_NODES) rs[node] = r0 + excl;
  if (b == 0 && t == 0) rs[N_NODES] = N_EDGES;
  __syncthreads();
  cur[t] = r0 + excl;
  __syncthreads();

  for (int e = r0 + t; e < r1; e += 256) {
    unsigned p = (unsigned)pairs[e];
    int pos = atomicAdd(&cur[p >> 24], 1);
    eidx[pos] = (int)(p & 0xFFFFFFu);
  }
}

// ---------------------------------------------------------------------------
// Dense GEMM: Uh[n] = feats[n] @ Wself, Zh[n] = feats[n] @ Wneigh (fp16 out,
// separate arrays so the gather's random working set is only Zh = 12.8MB).
// W rows read as 4x float4 ds_read_b128 (16B-aligned since joff%16==0).
// ---------------------------------------------------------------------------
__global__ __launch_bounds__(256) void gemm_uz(
    const float* __restrict__ feats, const float* __restrict__ Wself,
    const float* __restrict__ Wneigh, __half* __restrict__ Uh,
    __half* __restrict__ Zh) {
  __shared__ float As[MT * 65];
  __shared__ float Ws[64 * 128];
  int t = threadIdx.x;
  int mbase = blockIdx.x * MT;

  for (int i = t; i < 64 * 128; i += 256) {
    int k = i >> 7, j = i & 127;
    Ws[i] = (j < 64) ? Wself[k * 64 + j] : Wneigh[k * 64 + (j - 64)];
  }
#pragma unroll
  for (int s = 0; s < 8; s++) {
    int idx = (s * 256 + t) * 4;
    int m = idx >> 6, k = idx & 63;
    int gm = mbase + m;
    float4 v = (gm < N_NODES) ? *(const float4*)(feats + (size_t)gm * F + k)
                              : make_float4(0.f, 0.f, 0.f, 0.f);
    float* d = As + m * 65 + k;
    d[0] = v.x; d[1] = v.y; d[2] = v.z; d[3] = v.w;
  }
  __syncthreads();

  int wave = t >> 6, lane = t & 63;
  int jq = lane & 3, nq = lane >> 2;
  int half = wave & 1;
  int mb = (wave >> 1) * 64 + 4 * nq;          // 4 nodes: mb..mb+3
  int joff = half * 64 + jq * 16;              // 16 outputs: joff..joff+15

  float acc[4][16];
#pragma unroll
  for (int i = 0; i < 4; i++)
#pragma unroll
    for (int c = 0; c < 16; c++) acc[i][c] = 0.f;

#pragma unroll 4
  for (int k = 0; k < 64; k++) {
    float a0 = As[(mb + 0) * 65 + k];
    float a1 = As[(mb + 1) * 65 + k];
    float a2 = As[(mb + 2) * 65 + k];
    float a3 = As[(mb + 3) * 65 + k];
    const float4* wr = (const float4*)(Ws + k * 128 + joff);
    float4 w4[4];
    w4[0] = wr[0]; w4[1] = wr[1]; w4[2] = wr[2]; w4[3] = wr[3];
    const float* w = (const float*)w4;
#pragma unroll
    for (int c = 0; c < 16; c++) {
      float wv = w[c];
      acc[0][c] += a0 * wv;
      acc[1][c] += a1 * wv;
      acc[2][c] += a2 * wv;
      acc[3][c] += a3 * wv;
    }
  }

  __half* outp = half ? Zh : Uh;
  int jbase = jq * 16;
#pragma unroll
  for (int i = 0; i < 4; i++) {
    int gm = mbase + mb + i;
    if (gm < N_NODES) {
#pragma unroll
      for (int c4 = 0; c4 < 4; c4++) {
        union { __half h[4]; uint2 u; } pk;
        pk.h[0] = __float2half_rn(acc[i][c4 * 4 + 0]);
        pk.h[1] = __float2half_rn(acc[i][c4 * 4 + 1]);
        pk.h[2] = __float2half_rn(acc[i][c4 * 4 + 2]);
        pk.h[3] = __float2half_rn(acc[i][c4 * 4 + 3]);
        *(uint2*)(outp + (size_t)gm * F + jbase + c4 * 4) = pk.u;
      }
    }
  }
}

// ---------------------------------------------------------------------------
// Fused gather + SAGE update + ReLU + per-graph max readout, v2.
// Neighbor batches of 16: sub handles jj+sub+{0,4,8,12} -> 4 INDEPENDENT
// uint2 loads in flight per group (4x memory-level parallelism vs v1).
// ---------------------------------------------------------------------------
__global__ __launch_bounds__(256) void gather_h(
    const __half* __restrict__ Uh, const __half* __restrict__ Zh,
    const int* __restrict__ rs, const int* __restrict__ eidx,
    const float* __restrict__ bneigh, const int* __restrict__ gids,
    int* __restrict__ hgbits) {
  int lane = threadIdx.x & 63;
  int wid  = (blockIdx.x * blockDim.x + threadIdx.x) >> 6;
  const int NW = (2048 * 256) >> 6;                 // 8192 waves
  const int per = (N_NODES + NW - 1) / NW;          // 13 nodes/wave
  int n0 = wid * per;
  int n1 = n0 + per; if (n1 > N_NODES) n1 = N_NODES;
  if (n0 >= n1) return;
  int fl  = lane & 15;
  int sub = lane >> 4;
  float4 b4 = *(const float4*)(bneigh + 4 * fl);

  int curg = gids[n0];
  float4 gmax = {0.f, 0.f, 0.f, 0.f};

  for (int n = n0; n < n1; n++) {
    // issue U-row load early (consumed after the gather)
    uint2 ur = *(const uint2*)(Uh + (size_t)n * F + 4 * fl);
    int r0 = rs[n], r1 = rs[n + 1];
    float sx = 0.f, sy = 0.f, sz = 0.f, sw = 0.f;
    for (int base = r0; base < r1; base += 64) {
      int m = r1 - base; if (m > 64) m = 64;
      int myid = (lane < m) ? eidx[base + lane] : 0;
      for (int jj = 0; jj < m; jj += 16) {
        int j0 = jj + sub;                          // j0, j0+4, j0+8, j0+12
        int s0 = __shfl(myid, j0);
        int s1 = __shfl(myid, j0 + 4);
        int s2 = __shfl(myid, j0 + 8);
        int s3 = __shfl(myid, j0 + 12);
        uint2 z0 = *(const uint2*)(Zh + (size_t)s0 * F + 4 * fl);
        uint2 z1 = *(const uint2*)(Zh + (size_t)s1 * F + 4 * fl);
        uint2 z2 = *(const uint2*)(Zh + (size_t)s2 * F + 4 * fl);
        uint2 z3 = *(const uint2*)(Zh + (size_t)s3 * F + 4 * fl);
        if (j0 < m) {
          float2 f0 = __half22float2(*(__half2*)&z0.x);
          float2 f1 = __half22float2(*(__half2*)&z0.y);
          sx += f0.x; sy += f0.y; sz += f1.x; sw += f1.y;
        }
        if (j0 + 4 < m) {
          float2 f0 = __half22float2(*(__half2*)&z1.x);
          float2 f1 = __half22float2(*(__half2*)&z1.y);
          sx += f0.x; sy += f0.y; sz += f1.x; sw += f1.y;
        }
        if (j0 + 8 < m) {
          float2 f0 = __half22float2(*(__half2*)&z2.x);
          float2 f1 = __half22float2(*(__half2*)&z2.y);
          sx += f0.x; sy += f0.y; sz += f1.x; sw += f1.y;
        }
        if (j0 + 12 < m) {
          float2 f0 = __half22float2(*(__half2*)&z3.x);
          float2 f1 = __half22float2(*(__half2*)&z3.y);
          sx += f0.x; sy += f0.y; sz += f1.x; sw += f1.y;
        }
      }
    }
    sx += __shfl_xor(sx, 16); sy += __shfl_xor(sy, 16);
    sz += __shfl_xor(sz, 16); sw += __shfl_xor(sw, 16);
    sx += __shfl_xor(sx, 32); sy += __shfl_xor(sy, 32);
    sz += __shfl_xor(sz, 32); sw += __shfl_xor(sw, 32);
    float inv = 1.0f / fmaxf((float)(r1 - r0), 1.0f);

    int g = gids[n];                                // wave-uniform
    if (g != curg) {
      if (sub == 0) {
        int* hp = hgbits + (size_t)curg * F + 4 * fl;
        atomicMax(hp + 0, __float_as_int(gmax.x));
        atomicMax(hp + 1, __float_as_int(gmax.y));
        atomicMax(hp + 2, __float_as_int(gmax.z));
        atomicMax(hp + 3, __float_as_int(gmax.w));
      }
      curg = g; gmax = make_float4(0.f, 0.f, 0.f, 0.f);
    }

    float2 uf0 = __half22float2(*(__half2*)&ur.x);
    float2 uf1 = __half22float2(*(__half2*)&ur.y);
    gmax.x = fmaxf(gmax.x, fmaxf(uf0.x + sx * inv + b4.x, 0.f));
    gmax.y = fmaxf(gmax.y, fmaxf(uf0.y + sy * inv + b4.y, 0.f));
    gmax.z = fmaxf(gmax.z, fmaxf(uf1.x + sz * inv + b4.z, 0.f));
    gmax.w = fmaxf(gmax.w, fmaxf(uf1.y + sw * inv + b4.w, 0.f));
  }
  if (sub == 0) {
    int* hp = hgbits + (size_t)curg * F + 4 * fl;
    atomicMax(hp + 0, __float_as_int(gmax.x));
    atomicMax(hp + 1, __float_as_int(gmax.y));
    atomicMax(hp + 2, __float_as_int(gmax.z));
    atomicMax(hp + 3, __float_as_int(gmax.w));
  }
}

// ---------------------------------------------------------------------------
// MLP head: weights staged in LDS once, 8 graphs per block.
// ---------------------------------------------------------------------------
#define GPB 8
__global__ __launch_bounds__(128) void mlp(
    const float* __restrict__ hg,
    const float* __restrict__ W1, const float* __restrict__ b1,
    const float* __restrict__ g1, const float* __restrict__ be1,
    const float* __restrict__ rm1, const float* __restrict__ rv1,
    const float* __restrict__ W2, const float* __restrict__ b2,
    const float* __restrict__ g2, const float* __restrict__ be2,
    const float* __restrict__ rm2, const float* __restrict__ rv2,
    const float* __restrict__ W3, const float* __restrict__ b3,
    float* __restrict__ out) {
  __shared__ float W1s[64 * 128];
  __shared__ float W2s[128 * 64];
  __shared__ float W3s[64];
  __shared__ float sc1[128], sh1[128], b1s[128];
  __shared__ float sc2[64],  sh2[64],  b2s[64];
  __shared__ float s0[64], s1[128], s2[64];
  int t = threadIdx.x;

  for (int i = t; i < 64 * 128; i += 128) W1s[i] = W1[i];
  for (int i = t; i < 128 * 64; i += 128) W2s[i] = W2[i];
  if (t < 64) W3s[t] = W3[t];
  {
    float iv = rsqrtf(rv1[t] + BN_EPS);
    float sc = g1[t] * iv;
    sc1[t] = sc; sh1[t] = be1[t] - rm1[t] * sc; b1s[t] = b1[t];
  }
  if (t < 64) {
    float iv = rsqrtf(rv2[t] + BN_EPS);
    float sc = g2[t] * iv;
    sc2[t] = sc; sh2[t] = be2[t] - rm2[t] * sc; b2s[t] = b2[t];
  }
  __syncthreads();

  for (int gg = 0; gg < GPB; gg++) {
    int g = blockIdx.x * GPB + gg;
    if (t < 64) s0[t] = hg[(size_t)g * F + t];
    __syncthreads();
    {
      float acc = b1s[t];
      for (int i = 0; i < 64; i++) acc += s0[i] * W1s[i * 128 + t];
      acc = fmaxf(acc, 0.0f);
      s1[t] = acc * sc1[t] + sh1[t];
    }
    __syncthreads();
    if (t < 64) {
      float acc = b2s[t];
      for (int i = 0; i < 128; i++) acc += s1[i] * W2s[i * 64 + t];
      acc = fmaxf(acc, 0.0f);
      s2[t] = acc * sc2[t] + sh2[t];
    }
    __syncthreads();
    if (t < 64) {
      float p = s2[t] * W3s[t];
      for (int off = 32; off > 0; off >>= 1) p += __shfl_down(p, off);
      if (t == 0) out[g] = p + b3[0];
    }
    __syncthreads();
  }
}

// ---------------------------------------------------------------------------
extern "C" void kernel_launch(void* const* d_in, const int* in_sizes, int n_in,
                              void* d_out, int out_size, void* d_ws, size_t ws_size,
                              hipStream_t stream) {
  const float* feats  = (const float*)d_in[0];
  const int*   src    = (const int*)d_in[1];
  const int*   dst    = (const int*)d_in[2];
  const int*   gids   = (const int*)d_in[3];
  const float* Wself  = (const float*)d_in[4];
  const float* Wneigh = (const float*)d_in[5];
  const float* bneigh = (const float*)d_in[6];
  const float* W1  = (const float*)d_in[7];
  const float* b1  = (const float*)d_in[8];
  const float* g1  = (const float*)d_in[9];
  const float* be1 = (const float*)d_in[10];
  const float* rm1 = (const float*)d_in[11];
  const float* rv1 = (const float*)d_in[12];
  const float* W2  = (const float*)d_in[13];
  const float* b2  = (const float*)d_in[14];
  const float* g2  = (const float*)d_in[15];
  const float* be2 = (const float*)d_in[16];
  const float* rm2 = (const float*)d_in[17];
  const float* rv2 = (const float*)d_in[18];
  const float* W3  = (const float*)d_in[19];
  const float* b3  = (const float*)d_in[20];

  // ws layout: Uh | Zh | rs | bstart | bcnt | hgbits | Ct | pairs | eidx
  __half* Uh   = (__half*)d_ws;                      // N_NODES*64 halves
  __half* Zh   = Uh + (size_t)N_NODES * F;           // N_NODES*64 halves
  int* rs      = (int*)(Zh + (size_t)N_NODES * F);   // N_NODES+1
  int* bstart  = rs + (N_NODES + 1);                 // NBUCK+1
  int* bcnt    = bstart + (NBUCK + 1);               // NBUCK
  int* hgbits  = bcnt + NBUCK;                       // N_GRAPHS*F (zeroed in chist)
  int* Ct      = hgbits + (size_t)N_GRAPHS * F;      // NBLK*NBUCK
  int* pairs   = Ct + (size_t)NBLK * NBUCK;          // N_EDGES
  int* eidx    = pairs + N_EDGES;                    // N_EDGES

  chist<<<NBLK, 256, 0, stream>>>(dst, Ct, hgbits);
  cscan<<<NBUCK, NBLK, 0, stream>>>(Ct, bcnt);
  bscan<<<1, 512, 0, stream>>>(bcnt, bstart);
  cscat<<<NBLK, 256, 0, stream>>>(src, dst, Ct, bstart, pairs);
  gemm_uz<<<(N_NODES + MT - 1) / MT, 256, 0, stream>>>(feats, Wself, Wneigh,
                                                       Uh, Zh);
  place<<<NBUCK, 256, 0, stream>>>(pairs, bstart, rs, eidx);
  gather_h<<<2048, 256, 0, stream>>>(Uh, Zh, rs, eidx, bneigh, gids, hgbits);
  mlp<<<N_GRAPHS / GPB, 128, 0, stream>>>((const float*)hgbits,
                                          W1, b1, g1, be1, rm1, rv1,
                                          W2, b2, g2, be2, rm2, rv2, W3, b3,
                                          (float*)d_out);
}